// Round 6
// baseline (218.108 us; speedup 1.0000x reference)
//
#include <hip/hip_runtime.h>

#define NV    150000
#define CIN   32
#define COUT  64
#define EPSF  1e-5f
#define NCOPY 16

#define NTHR   256
#define NBLK1  1172
#define NWAVE1 (NBLK1 * 4)            // 4688 waves, ~2 tiles each
#define NTILES (NV / 16)              // 9375 exact

#define NBLK2  2048
#define TOTAL4 ((long)NV * COUT / 4)  // 2,400,000 float4 chunks
#define STRIDE2 ((long)NBLK2 * NTHR)  // 524288 (multiple of 16)

typedef short  bf16x8 __attribute__((ext_vector_type(8)));
typedef float  f32x4  __attribute__((ext_vector_type(4)));

__device__ __forceinline__ short f2bf(float x) {
    union { float f; unsigned u; } c; c.f = x;
    return (short)((c.u + 0x7FFFu + ((c.u >> 16) & 1u)) >> 16);
}

// ---------------------------------------------------------------------------
// K1: one wave per 16-voxel tile (grid-stride). Center tap via MFMA with
// W[13] held in registers; off-center taps ballot-compacted and accumulated
// into the same register accumulators (gather form: all targets are in-tile).
// Fused BN partial sums -> striped global atomics.
// ---------------------------------------------------------------------------
__global__ __launch_bounds__(NTHR) void k_conv(
    const float* __restrict__ feat,    // [NV, CIN]
    const float* __restrict__ weight,  // [27, CIN, COUT]
    const int*   __restrict__ nbr,     // [27, NV]
    float*       __restrict__ out,     // [NV, COUT]
    float*       __restrict__ gstats)  // [NCOPY][128]
{
    const int tid  = threadIdx.x;
    const int lane = tid & 63;
    const int quad = lane >> 4;
    const int lm   = lane & 15;
    const int wid  = blockIdx.x * 4 + (tid >> 6);

    // B-fragments for W13: lane holds k = quad*8+j, n = b*16+lm.
    bf16x8 bfr[4];
#pragma unroll
    for (int b = 0; b < 4; ++b) {
        const float* wsrc = weight + 13 * CIN * COUT + (quad * 8) * COUT + b * 16 + lm;
#pragma unroll
        for (int j = 0; j < 8; ++j) bfr[b][j] = f2bf(wsrc[j * COUT]);
    }

    f32x4 ssum = {0.f, 0.f, 0.f, 0.f};   // per-lane BN sums, channel b*16+lm
    f32x4 qsum = {0.f, 0.f, 0.f, 0.f};

    for (int tile = wid; tile < NTILES; tile += NWAVE1) {
        const int v0 = tile * 16;

        // ---- center MFMA: A[m=lm][k=quad*8+j] = feat[v0+lm][quad*8+j] ----
        const float4* fp = (const float4*)(feat + (long)(v0 + lm) * CIN + quad * 8);
        const float4 fa = fp[0];
        const float4 fb = fp[1];
        bf16x8 afr;
        afr[0] = f2bf(fa.x); afr[1] = f2bf(fa.y); afr[2] = f2bf(fa.z); afr[3] = f2bf(fa.w);
        afr[4] = f2bf(fb.x); afr[5] = f2bf(fb.y); afr[6] = f2bf(fb.z); afr[7] = f2bf(fb.w);

        f32x4 acc[4];
#pragma unroll
        for (int b = 0; b < 4; ++b) {
            const f32x4 z = {0.f, 0.f, 0.f, 0.f};
            acc[b] = __builtin_amdgcn_mfma_f32_16x16x32_bf16(afr, bfr[b], z, 0, 0, 0);
        }

        // ---- scan 26 off-center taps: 416 items across 7 ballots ----
        int idxs[7];
#pragma unroll
        for (int it = 0; it < 7; ++it) {
            const int item = lane + it * 64;
            int idx = -1;
            if (item < 416) {
                const int kp = item >> 4;
                const int k  = kp + (kp >= 13);
                idx = nbr[(long)k * NV + v0 + (item & 15)];
            }
            idxs[it] = idx;
        }

        // ---- drain active pairs (all targets in this tile) ----
#pragma unroll 1
        for (int it = 0; it < 7; ++it) {
            unsigned long long m = __ballot(idxs[it] >= 0);
            while (m) {
                const int bit = __ffsll((long long)m) - 1;
                m &= m - 1ull;
                const int idx  = __shfl(idxs[it], bit);
                const int item = it * 64 + bit;
                const int kp   = item >> 4;
                const int k    = kp + (kp >= 13);
                const int vrow = item & 15;

                // lane = output channel; 64-lane dot product over CIN
                const float fv = feat[(long)idx * CIN + (lane & 31)];
                const float* wk = weight + (long)k * CIN * COUT + lane;
                float contrib = 0.f;
#pragma unroll
                for (int c = 0; c < CIN; ++c)
                    contrib += __shfl(fv, c) * wk[c * COUT];

                // redistribute into MFMA accumulator layout
                const int cq = vrow >> 2, cr = vrow & 3;
#pragma unroll
                for (int b = 0; b < 4; ++b) {
                    const float val = __shfl(contrib, b * 16 + lm);
                    if (quad == cq) {
                        if      (cr == 0) acc[b][0] += val;
                        else if (cr == 1) acc[b][1] += val;
                        else if (cr == 2) acc[b][2] += val;
                        else              acc[b][3] += val;
                    }
                }
            }
        }

        // ---- store rows + accumulate BN partials from final values ----
#pragma unroll
        for (int b = 0; b < 4; ++b) {
            const float r0 = acc[b][0], r1 = acc[b][1], r2 = acc[b][2], r3 = acc[b][3];
            out[(long)(v0 + quad * 4 + 0) * COUT + b * 16 + lm] = r0;
            out[(long)(v0 + quad * 4 + 1) * COUT + b * 16 + lm] = r1;
            out[(long)(v0 + quad * 4 + 2) * COUT + b * 16 + lm] = r2;
            out[(long)(v0 + quad * 4 + 3) * COUT + b * 16 + lm] = r3;
            ssum[b] += r0 + r1 + r2 + r3;
            qsum[b] += r0 * r0 + r1 * r1 + r2 * r2 + r3 * r3;
        }
    }

    // ---- butterfly over the 4 quads (same channel b*16+lm) ----
#pragma unroll
    for (int off = 16; off < 64; off <<= 1) {
#pragma unroll
        for (int b = 0; b < 4; ++b) {
            ssum[b] += __shfl_xor(ssum[b], off);
            qsum[b] += __shfl_xor(qsum[b], off);
        }
    }

    __shared__ float ls[4][128];
    const int wv = tid >> 6;
    if (quad == 0) {
#pragma unroll
        for (int b = 0; b < 4; ++b) {
            ls[wv][b * 16 + lm]      = ssum[b];
            ls[wv][64 + b * 16 + lm] = qsum[b];
        }
    }
    __syncthreads();
    if (tid < 128) {
        const float v = ls[0][tid] + ls[1][tid] + ls[2][tid] + ls[3][tid];
        atomicAdd(gstats + (blockIdx.x & (NCOPY - 1)) * 128 + tid, v);
    }
}

// ---------------------------------------------------------------------------
// K2: redundant per-block stripe reduce -> scale/shift, then in-place
// affine + ReLU over out.
// ---------------------------------------------------------------------------
__global__ __launch_bounds__(NTHR) void k_norm(
    float*       __restrict__ out,
    const float* __restrict__ gstats,
    const float* __restrict__ gamma,
    const float* __restrict__ beta)
{
    __shared__ float sscale[COUT];
    __shared__ float sshift[COUT];
    const int tid = threadIdx.x;
    if (tid < COUT) {
        float s = 0.f, q = 0.f;
#pragma unroll
        for (int cp = 0; cp < NCOPY; ++cp) {
            s += gstats[cp * 128 + tid];
            q += gstats[cp * 128 + 64 + tid];
        }
        const float inv_n = 1.f / (float)NV;
        const float mean = s * inv_n;
        float var = q * inv_n - mean * mean;
        var = fmaxf(var, 0.f);
        const float rstd = rsqrtf(var + EPSF);
        const float sc = gamma[tid] * rstd;
        sscale[tid] = sc;
        sshift[tid] = beta[tid] - mean * sc;
    }
    __syncthreads();

    const int g4 = (tid & 15) * 4;
    const float4 SC = make_float4(sscale[g4], sscale[g4 + 1], sscale[g4 + 2], sscale[g4 + 3]);
    const float4 SH = make_float4(sshift[g4], sshift[g4 + 1], sshift[g4 + 2], sshift[g4 + 3]);

    float4* o4 = (float4*)out;
    for (long i = (long)blockIdx.x * NTHR + tid; i < TOTAL4; i += STRIDE2) {
        float4 v = o4[i];
        v.x = fmaxf(v.x * SC.x + SH.x, 0.f);
        v.y = fmaxf(v.y * SC.y + SH.y, 0.f);
        v.z = fmaxf(v.z * SC.z + SH.z, 0.f);
        v.w = fmaxf(v.w * SC.w + SH.w, 0.f);
        o4[i] = v;
    }
}

// ---------------------------------------------------------------------------
extern "C" void kernel_launch(void* const* d_in, const int* in_sizes, int n_in,
                              void* d_out, int out_size, void* d_ws, size_t ws_size,
                              hipStream_t stream) {
    const float* feat   = (const float*)d_in[0];
    const float* weight = (const float*)d_in[1];
    const float* gamma  = (const float*)d_in[2];
    const float* beta   = (const float*)d_in[3];
    const int*   nbr    = (const int*)d_in[4];
    float* out = (float*)d_out;

    float* gstats = (float*)d_ws;   // NCOPY * 128 floats = 8 KB

    hipMemsetAsync(d_ws, 0, NCOPY * 128 * sizeof(float), stream);

    k_conv<<<NBLK1, NTHR, 0, stream>>>(feat, weight, nbr, out, gstats);
    k_norm<<<NBLK2, NTHR, 0, stream>>>(out, gstats, gamma, beta);
}

// Round 7
// 127.377 us; speedup vs baseline: 1.7123x; 1.7123x over previous
//
#include <hip/hip_runtime.h>

#define NV    150000
#define CIN   32
#define COUT  64
#define EPSF  1e-5f
#define NCOPY 16

#define NTHR   256
#define NTILES (NV / 16)              // 9375 exact
#define NBLK1  ((NTILES + 3) / 4)     // 2344 blocks, 1 tile per wave

#define NBLK2  2048
#define TOTAL4 ((long)NV * COUT / 4)  // 2,400,000 float4 chunks
#define STRIDE2 ((long)NBLK2 * NTHR)

typedef short  bf16x8 __attribute__((ext_vector_type(8)));
typedef float  f32x4  __attribute__((ext_vector_type(4)));

__device__ __forceinline__ short f2bf(float x) {
    union { float f; unsigned u; } c; c.f = x;
    return (short)((c.u + 0x7FFFu + ((c.u >> 16) & 1u)) >> 16);
}

// ---------------------------------------------------------------------------
// K1: one wave per 16-voxel tile. Center tap via MFMA (W13 in registers).
// Off-center taps: ballot -> wave-uniform 26-bit active-k mask; per active k,
// masked gather of neighbor rows into an MFMA A-fragment + W[k] B-fragments
// (L2-resident) -> 4 accumulating MFMAs. Fused BN partials -> striped atomics.
// ---------------------------------------------------------------------------
__global__ __launch_bounds__(NTHR) void k_conv(
    const float* __restrict__ feat,    // [NV, CIN]
    const float* __restrict__ weight,  // [27, CIN, COUT]
    const int*   __restrict__ nbr,     // [27, NV]
    float*       __restrict__ out,     // [NV, COUT]
    float*       __restrict__ gstats)  // [NCOPY][128]
{
    const int tid  = threadIdx.x;
    const int lane = tid & 63;
    const int quad = lane >> 4;
    const int lm   = lane & 15;
    const int wid  = blockIdx.x * 4 + (tid >> 6);   // == tile id

    f32x4 ssum = {0.f, 0.f, 0.f, 0.f};
    f32x4 qsum = {0.f, 0.f, 0.f, 0.f};

    const bool have_tile = (wid < NTILES);
    f32x4 acc[4] = {{0.f,0.f,0.f,0.f},{0.f,0.f,0.f,0.f},{0.f,0.f,0.f,0.f},{0.f,0.f,0.f,0.f}};
    const int v0 = have_tile ? wid * 16 : 0;

    if (have_tile) {
        // ---- center tap: B = W13 (registers), A = feat rows of this tile ----
        bf16x8 bfr;
        f32x4  z = {0.f, 0.f, 0.f, 0.f};
        {
            const float4* fp = (const float4*)(feat + (long)(v0 + lm) * CIN + quad * 8);
            const float4 fa = fp[0];
            const float4 fb = fp[1];
            bf16x8 afr;
            afr[0] = f2bf(fa.x); afr[1] = f2bf(fa.y); afr[2] = f2bf(fa.z); afr[3] = f2bf(fa.w);
            afr[4] = f2bf(fb.x); afr[5] = f2bf(fb.y); afr[6] = f2bf(fb.z); afr[7] = f2bf(fb.w);
#pragma unroll
            for (int b = 0; b < 4; ++b) {
                const float* wsrc = weight + 13 * CIN * COUT + (quad * 8) * COUT + b * 16 + lm;
#pragma unroll
                for (int j = 0; j < 8; ++j) bfr[j] = f2bf(wsrc[j * COUT]);
                acc[b] = __builtin_amdgcn_mfma_f32_16x16x32_bf16(afr, bfr, acc[b], 0, 0, 0);
            }
        }

        // ---- ballot-scan 26 off-center taps (416 items over 7 loads) ----
        unsigned int kmask = 0u;
#pragma unroll
        for (int it = 0; it < 7; ++it) {
            const int item = lane + it * 64;
            int idx = -1;
            if (item < 416) {
                const int kp = item >> 4;
                const int k  = kp + (kp >= 13);
                idx = nbr[(long)k * NV + v0 + (item & 15)];
            }
            const unsigned long long m = __ballot(idx >= 0);
            kmask |= ((m & 0xFFFFull)         ? 1u : 0u) << (it * 4 + 0);
            kmask |= (((m >> 16) & 0xFFFFull) ? 1u : 0u) << (it * 4 + 1);
            kmask |= (((m >> 32) & 0xFFFFull) ? 1u : 0u) << (it * 4 + 2);
            kmask |= ((m >> 48)               ? 1u : 0u) << (it * 4 + 3);
        }

        // ---- per active k: masked-gather A + W[k] B-frags + 4 MFMAs ----
        while (kmask) {
            const int kp = __ffs(kmask) - 1;
            kmask &= kmask - 1u;
            const int k = kp + (kp >= 13);

            const int idxv = nbr[(long)k * NV + v0 + lm];   // L1/L2 hit
            const float4* fp = (const float4*)(feat + (long)(idxv < 0 ? 0 : idxv) * CIN + quad * 8);
            float4 ga = fp[0];
            float4 gb = fp[1];
            if (idxv < 0) {
                ga = make_float4(0.f, 0.f, 0.f, 0.f);
                gb = make_float4(0.f, 0.f, 0.f, 0.f);
            }
            bf16x8 na;
            na[0] = f2bf(ga.x); na[1] = f2bf(ga.y); na[2] = f2bf(ga.z); na[3] = f2bf(ga.w);
            na[4] = f2bf(gb.x); na[5] = f2bf(gb.y); na[6] = f2bf(gb.z); na[7] = f2bf(gb.w);

            const float* wk = weight + (long)k * CIN * COUT + (quad * 8) * COUT + lm;
            bf16x8 wb0, wb1, wb2, wb3;
#pragma unroll
            for (int j = 0; j < 8; ++j) {
                const float* wr = wk + j * COUT;
                wb0[j] = f2bf(wr[0]);
                wb1[j] = f2bf(wr[16]);
                wb2[j] = f2bf(wr[32]);
                wb3[j] = f2bf(wr[48]);
            }
            acc[0] = __builtin_amdgcn_mfma_f32_16x16x32_bf16(na, wb0, acc[0], 0, 0, 0);
            acc[1] = __builtin_amdgcn_mfma_f32_16x16x32_bf16(na, wb1, acc[1], 0, 0, 0);
            acc[2] = __builtin_amdgcn_mfma_f32_16x16x32_bf16(na, wb2, acc[2], 0, 0, 0);
            acc[3] = __builtin_amdgcn_mfma_f32_16x16x32_bf16(na, wb3, acc[3], 0, 0, 0);
        }

        // ---- store rows + BN partials from final values ----
#pragma unroll
        for (int b = 0; b < 4; ++b) {
            const float r0 = acc[b][0], r1 = acc[b][1], r2 = acc[b][2], r3 = acc[b][3];
            out[(long)(v0 + quad * 4 + 0) * COUT + b * 16 + lm] = r0;
            out[(long)(v0 + quad * 4 + 1) * COUT + b * 16 + lm] = r1;
            out[(long)(v0 + quad * 4 + 2) * COUT + b * 16 + lm] = r2;
            out[(long)(v0 + quad * 4 + 3) * COUT + b * 16 + lm] = r3;
            ssum[b] += r0 + r1 + r2 + r3;
            qsum[b] += r0 * r0 + r1 * r1 + r2 * r2 + r3 * r3;
        }
    }

    // ---- butterfly over quads (same channel b*16+lm across quads) ----
#pragma unroll
    for (int off = 16; off < 64; off <<= 1) {
#pragma unroll
        for (int b = 0; b < 4; ++b) {
            ssum[b] += __shfl_xor(ssum[b], off);
            qsum[b] += __shfl_xor(qsum[b], off);
        }
    }

    __shared__ float ls[4][128];
    const int wv = tid >> 6;
    if (quad == 0) {
#pragma unroll
        for (int b = 0; b < 4; ++b) {
            ls[wv][b * 16 + lm]      = ssum[b];
            ls[wv][64 + b * 16 + lm] = qsum[b];
        }
    }
    __syncthreads();
    if (tid < 128) {
        const float v = ls[0][tid] + ls[1][tid] + ls[2][tid] + ls[3][tid];
        atomicAdd(gstats + (blockIdx.x & (NCOPY - 1)) * 128 + tid, v);
    }
}

// ---------------------------------------------------------------------------
// K2: redundant per-block stripe reduce -> scale/shift, then in-place
// affine + ReLU over out.
// ---------------------------------------------------------------------------
__global__ __launch_bounds__(NTHR) void k_norm(
    float*       __restrict__ out,
    const float* __restrict__ gstats,
    const float* __restrict__ gamma,
    const float* __restrict__ beta)
{
    __shared__ float sscale[COUT];
    __shared__ float sshift[COUT];
    const int tid = threadIdx.x;
    if (tid < COUT) {
        float s = 0.f, q = 0.f;
#pragma unroll
        for (int cp = 0; cp < NCOPY; ++cp) {
            s += gstats[cp * 128 + tid];
            q += gstats[cp * 128 + 64 + tid];
        }
        const float inv_n = 1.f / (float)NV;
        const float mean = s * inv_n;
        float var = q * inv_n - mean * mean;
        var = fmaxf(var, 0.f);
        const float rstd = rsqrtf(var + EPSF);
        const float sc = gamma[tid] * rstd;
        sscale[tid] = sc;
        sshift[tid] = beta[tid] - mean * sc;
    }
    __syncthreads();

    const int g4 = (tid & 15) * 4;
    const float4 SC = make_float4(sscale[g4], sscale[g4 + 1], sscale[g4 + 2], sscale[g4 + 3]);
    const float4 SH = make_float4(sshift[g4], sshift[g4 + 1], sshift[g4 + 2], sshift[g4 + 3]);

    float4* o4 = (float4*)out;
    for (long i = (long)blockIdx.x * NTHR + tid; i < TOTAL4; i += STRIDE2) {
        float4 v = o4[i];
        v.x = fmaxf(v.x * SC.x + SH.x, 0.f);
        v.y = fmaxf(v.y * SC.y + SH.y, 0.f);
        v.z = fmaxf(v.z * SC.z + SH.z, 0.f);
        v.w = fmaxf(v.w * SC.w + SH.w, 0.f);
        o4[i] = v;
    }
}

// ---------------------------------------------------------------------------
extern "C" void kernel_launch(void* const* d_in, const int* in_sizes, int n_in,
                              void* d_out, int out_size, void* d_ws, size_t ws_size,
                              hipStream_t stream) {
    const float* feat   = (const float*)d_in[0];
    const float* weight = (const float*)d_in[1];
    const float* gamma  = (const float*)d_in[2];
    const float* beta   = (const float*)d_in[3];
    const int*   nbr    = (const int*)d_in[4];
    float* out = (float*)d_out;

    float* gstats = (float*)d_ws;   // NCOPY * 128 floats = 8 KB

    hipMemsetAsync(d_ws, 0, NCOPY * 128 * sizeof(float), stream);

    k_conv<<<NBLK1, NTHR, 0, stream>>>(feat, weight, nbr, out, gstats);
    k_norm<<<NBLK2, NTHR, 0, stream>>>(out, gstats, gamma, beta);
}